// Round 2
// baseline (118.479 us; speedup 1.0000x reference)
//
#include <hip/hip_runtime.h>

#define HID 768
#define NTHREADS 256
#define WPB 4          // waves per block = steps processed in parallel per token
#define RTHREADS 256   // reduce kernel block size

// One block per token t; wave w handles path steps d = w, w+4, w+8, ...
//
// v2 -> v3: the per-step dependent chain (mask byte -> path_nodes -> W row)
// is collapsed by loading ALL path metadata for the token once per block:
// lane d holds {mask, node, bit, bias.xy} for step d (D ~ 20 << 64), and
// depth = popcount(ballot(mask)) since mask is a prefix. Per-step lookups
// become __shfl broadcasts (no memory). The only per-step memory op is the
// 6x float4 W-row load, 1-deep software-pipelined. The wasted clamped
// prefetch on each wave's last step is skipped via a wave-uniform branch
// (S is wave-uniform), saving ~48 MB of redundant L2 broadcast traffic.
__global__ __launch_bounds__(NTHREADS) void huffman_token_kernel(
    const float* __restrict__ hidden,       // [T, H]
    const int*   __restrict__ target,       // [T]
    const float* __restrict__ node_W,       // [V-1, H, 2]
    const float* __restrict__ node_b,       // [V-1, 2]
    const int*   __restrict__ path_nodes,   // [V, D]
    const int*   __restrict__ path_bits,    // [V, D]
    const void*  __restrict__ path_mask,    // [V, D] bool (byte OR int32 layout)
    float*       __restrict__ partial,      // [T * WPB]
    int D)
{
    const int t    = blockIdx.x;
    const int wave = threadIdx.x >> 6;
    const int lane = threadIdx.x & 63;

    // Mask layout detect: mask[0,0..3] all true (min Huffman depth >> 4),
    // so byte layout reads 0x01010101, int32 layout reads 1.
    const bool mask_is_byte = (*(const unsigned int*)path_mask) > 1u;

    const int v = target[t];                     // block-uniform scalar
    const long pbase = (long)v * D;

    // ---- per-lane path metadata: lane d owns step d (requires D <= 64;
    //      padded Huffman depth here is ~20) ----
    bool  my_m = false;
    int   my_n = 0, my_bit = 0;
    float my_b0 = 0.0f, my_b1 = 0.0f;
    if (lane < D) {
        my_m = mask_is_byte
            ? (((const unsigned char*)path_mask)[pbase + lane] != 0)
            : (((const int*)path_mask)[pbase + lane] != 0);
        if (my_m) {
            my_n   = path_nodes[pbase + lane];
            my_bit = path_bits[pbase + lane];
            const float2 b2 = ((const float2*)node_b)[my_n];
            my_b0 = b2.x; my_b1 = b2.y;
        }
    }
    const int depth = __popcll(__ballot(my_m));  // mask is a prefix in d

    // h[t] into registers: lane owns k-pairs p = j*64 + lane (k = 2p, 2p+1).
    const float2* __restrict__ h2 = (const float2*)(hidden + (long)t * HID);
    float2 h[6];
    #pragma unroll
    for (int j = 0; j < 6; ++j) h[j] = h2[j * 64 + lane];

    float sum = 0.0f;

    const int S = (depth > wave) ? ((depth - wave + WPB - 1) / WPB) : 0;
    if (S > 0) {
        int d = wave;
        int n = __shfl(my_n, d, 64);

        float4 w[6];
        {
            const float4* __restrict__ w4 =
                (const float4*)(node_W + (long)n * (HID * 2));
            #pragma unroll
            for (int j = 0; j < 6; ++j) w[j] = w4[j * 64 + lane];
        }

        for (int i = 0; i < S; ++i) {
            // ---- prefetch next step's W row (skip on last step; S is
            //      wave-uniform so this branch is scalar) ----
            const int dn = d + WPB;
            float4 wn[6];
            if (i + 1 < S) {
                const int nn = __shfl(my_n, dn, 64);
                const float4* __restrict__ w4n =
                    (const float4*)(node_W + (long)nn * (HID * 2));
                #pragma unroll
                for (int j = 0; j < 6; ++j) wn[j] = w4n[j * 64 + lane];
            }

            // ---- compute current step ----
            float acc0 = 0.0f, acc1 = 0.0f;
            #pragma unroll
            for (int j = 0; j < 6; ++j) {   // w = W[n,2p,{0,1}], W[n,2p+1,{0,1}]
                acc0 += h[j].x * w[j].x + h[j].y * w[j].z;
                acc1 += h[j].x * w[j].y + h[j].y * w[j].w;
            }
            #pragma unroll
            for (int off = 32; off > 0; off >>= 1) {
                acc0 += __shfl_xor(acc0, off, 64);
                acc1 += __shfl_xor(acc1, off, 64);
            }

            // Per-step scalars via register broadcast (no memory).
            const float b0  = __shfl(my_b0, d, 64);
            const float b1  = __shfl(my_b1, d, 64);
            const int   bit = __shfl(my_bit, d, 64);

            // Double-softmax CE (faithful to reference), redundant per lane.
            const float l0  = acc0 + b0;
            const float l1  = acc1 + b1;
            const float m   = fmaxf(l0, l1);
            const float e0  = __expf(l0 - m);
            const float e1  = __expf(l1 - m);
            const float s   = e0 + e1;
            const float p0  = e0 / s;
            const float p1  = e1 / s;
            const float lse = __logf(__expf(p0) + __expf(p1));
            const float pb  = bit ? p1 : p0;
            sum += lse - pb;

            // ---- rotate ----
            d = dn;
            if (i + 1 < S) {
                #pragma unroll
                for (int j = 0; j < 6; ++j) w[j] = wn[j];
            }
        }
    }

    if (lane == 0) partial[t * WPB + wave] = sum;  // every slot written (ws poisoned)
}

// Single-block reduce of n floats (n % 4 == 0) -> out[0].
__global__ __launch_bounds__(RTHREADS) void huffman_reduce_kernel(
    const float* __restrict__ partial, float* __restrict__ out, int n4)
{
    const float4* __restrict__ p4 = (const float4*)partial;
    float s = 0.0f;
    for (int i = threadIdx.x; i < n4; i += RTHREADS) {
        const float4 v = p4[i];
        s += (v.x + v.y) + (v.z + v.w);
    }
    #pragma unroll
    for (int off = 32; off > 0; off >>= 1) s += __shfl_xor(s, off, 64);
    __shared__ float ws[RTHREADS / 64];
    if ((threadIdx.x & 63) == 0) ws[threadIdx.x >> 6] = s;
    __syncthreads();
    if (threadIdx.x == 0) {
        float tot = 0.0f;
        #pragma unroll
        for (int w = 0; w < RTHREADS / 64; ++w) tot += ws[w];
        out[0] = tot;
    }
}

extern "C" void kernel_launch(void* const* d_in, const int* in_sizes, int n_in,
                              void* d_out, int out_size, void* d_ws, size_t ws_size,
                              hipStream_t stream) {
    const float* hidden     = (const float*)d_in[0];
    const int*   target     = (const int*)d_in[1];
    const float* node_W     = (const float*)d_in[2];
    const float* node_b     = (const float*)d_in[3];
    const int*   path_nodes = (const int*)d_in[4];
    const int*   path_bits  = (const int*)d_in[5];
    const void*  path_mask  = (const void*)d_in[6];
    float* out = (float*)d_out;
    float* partial = (float*)d_ws;

    const int T   = in_sizes[0] / HID;        // B*S = 2048 (in_sizes are elem counts)
    const int Vm1 = in_sizes[3] / 2;          // V-1
    const int V   = Vm1 + 1;
    const int D   = in_sizes[4] / V;          // padded path depth (~20)

    const int nslot = T * WPB;                // 8192, multiple of 4

    huffman_token_kernel<<<dim3(T), dim3(NTHREADS), 0, stream>>>(
        hidden, target, node_W, node_b, path_nodes, path_bits, path_mask,
        partial, D);

    huffman_reduce_kernel<<<dim3(1), dim3(RTHREADS), 0, stream>>>(
        partial, out, nslot / 4);
}

// Round 3
// 116.626 us; speedup vs baseline: 1.0159x; 1.0159x over previous
//
#include <hip/hip_runtime.h>

#define HID 768
#define NTHREADS 256
#define WPB 4          // waves per block = steps processed in parallel per token
#define RTHREADS 256   // reduce kernel block size

// One block per token t; wave w handles path steps d = w, w+4, w+8, ...
//
// v3 -> v4: occupancy play. The 1-deep W prefetch (+24 VGPRs) pushed the
// kernel to ~85 VGPRs -> 4 waves/SIMD, leaving ~600 cy of exposed HBM
// latency per step marginally covered. v4 drops the prefetch and targets
// <=64 VGPRs (__launch_bounds__(256,8)) for 8 waves/SIMD: latency is
// hidden by wave interleaving (TLP) instead of per-wave pipelining.
// Supporting trims:
//  - per-step metadata via v_readlane -> SGPRs (wave-uniform d), which
//    also scalarizes the W row base address;
//  - packed 7-shuffle reduction: fold lane^32 carrying acc0 in lanes<32
//    and acc1 in lanes>=32, 5-level butterfly within halves, one swap.
//    Same pairwise combine tree as the old 6-level butterflies =>
//    bit-identical sums (absmax stays 0).
__global__ __launch_bounds__(NTHREADS, 8) void huffman_token_kernel(
    const float* __restrict__ hidden,       // [T, H]
    const int*   __restrict__ target,       // [T]
    const float* __restrict__ node_W,       // [V-1, H, 2]
    const float* __restrict__ node_b,       // [V-1, 2]
    const int*   __restrict__ path_nodes,   // [V, D]
    const int*   __restrict__ path_bits,    // [V, D]
    const void*  __restrict__ path_mask,    // [V, D] bool (byte OR int32 layout)
    float*       __restrict__ partial,      // [T * WPB]
    int D)
{
    const int t    = blockIdx.x;
    const int wave = threadIdx.x >> 6;
    const int lane = threadIdx.x & 63;

    // Mask layout detect: mask[0,0..3] all true (min Huffman depth >> 4),
    // so byte layout reads 0x01010101, int32 layout reads 1.
    const bool mask_is_byte = (*(const unsigned int*)path_mask) > 1u;

    const int v = target[t];                     // block-uniform scalar
    const long pbase = (long)v * D;

    // Per-lane path metadata: lane d owns step d (requires D <= 64; here ~20).
    bool  my_m = false;
    int   my_n = 0, my_bit = 0;
    float my_b0 = 0.0f, my_b1 = 0.0f;
    if (lane < D) {
        my_m = mask_is_byte
            ? (((const unsigned char*)path_mask)[pbase + lane] != 0)
            : (((const int*)path_mask)[pbase + lane] != 0);
        if (my_m) {
            my_n   = path_nodes[pbase + lane];
            my_bit = path_bits[pbase + lane];
            const float2 b2 = ((const float2*)node_b)[my_n];
            my_b0 = b2.x; my_b1 = b2.y;
        }
    }
    const int depth = __popcll(__ballot(my_m));  // mask is a prefix in d

    // h[t] into registers: lane owns k-pairs p = j*64 + lane (k = 2p, 2p+1).
    const float2* __restrict__ h2 = (const float2*)(hidden + (long)t * HID);
    float2 h[6];
    #pragma unroll
    for (int j = 0; j < 6; ++j) h[j] = h2[j * 64 + lane];

    float sum = 0.0f;

    for (int d = wave; d < depth; d += WPB) {
        // Wave-uniform per-step scalars straight into SGPRs.
        const int   n   = __builtin_amdgcn_readlane(my_n, d);
        const int   bit = __builtin_amdgcn_readlane(my_bit, d);
        const float b0  = __uint_as_float(
            __builtin_amdgcn_readlane(__float_as_uint(my_b0), d));
        const float b1  = __uint_as_float(
            __builtin_amdgcn_readlane(__float_as_uint(my_b1), d));

        const float4* __restrict__ w4 =
            (const float4*)(node_W + (long)n * (HID * 2));
        float4 w[6];
        #pragma unroll
        for (int j = 0; j < 6; ++j) w[j] = w4[j * 64 + lane];

        float acc0 = 0.0f, acc1 = 0.0f;
        #pragma unroll
        for (int j = 0; j < 6; ++j) {       // w = W[n,2p,{0,1}], W[n,2p+1,{0,1}]
            acc0 += h[j].x * w[j].x + h[j].y * w[j].z;
            acc1 += h[j].x * w[j].y + h[j].y * w[j].w;
        }

        // Packed 7-shuffle reduction (bit-identical to two 6-level butterflies).
        float r     = (lane < 32) ? acc0 : acc1;
        float other = (lane < 32) ? acc1 : acc0;
        r += __shfl_xor(other, 32, 64);     // fold lane^32 for both outputs
        #pragma unroll
        for (int off = 16; off > 0; off >>= 1) r += __shfl_xor(r, off, 64);
        const float ro = __shfl_xor(r, 32, 64);
        const float A0 = (lane < 32) ? r  : ro;
        const float A1 = (lane < 32) ? ro : r;

        // Double-softmax CE (faithful to reference), redundant per lane.
        const float l0  = A0 + b0;
        const float l1  = A1 + b1;
        const float m   = fmaxf(l0, l1);
        const float e0  = __expf(l0 - m);
        const float e1  = __expf(l1 - m);
        const float s   = e0 + e1;
        const float p0  = e0 / s;
        const float p1  = e1 / s;
        const float lse = __logf(__expf(p0) + __expf(p1));
        const float pb  = bit ? p1 : p0;
        sum += lse - pb;
    }

    if (lane == 0) partial[t * WPB + wave] = sum;  // every slot written (ws poisoned)
}

// Single-block reduce of n floats (n % 4 == 0) -> out[0].
__global__ __launch_bounds__(RTHREADS) void huffman_reduce_kernel(
    const float* __restrict__ partial, float* __restrict__ out, int n4)
{
    const float4* __restrict__ p4 = (const float4*)partial;
    float s = 0.0f;
    for (int i = threadIdx.x; i < n4; i += RTHREADS) {
        const float4 v = p4[i];
        s += (v.x + v.y) + (v.z + v.w);
    }
    #pragma unroll
    for (int off = 32; off > 0; off >>= 1) s += __shfl_xor(s, off, 64);
    __shared__ float ws[RTHREADS / 64];
    if ((threadIdx.x & 63) == 0) ws[threadIdx.x >> 6] = s;
    __syncthreads();
    if (threadIdx.x == 0) {
        float tot = 0.0f;
        #pragma unroll
        for (int w = 0; w < RTHREADS / 64; ++w) tot += ws[w];
        out[0] = tot;
    }
}

extern "C" void kernel_launch(void* const* d_in, const int* in_sizes, int n_in,
                              void* d_out, int out_size, void* d_ws, size_t ws_size,
                              hipStream_t stream) {
    const float* hidden     = (const float*)d_in[0];
    const int*   target     = (const int*)d_in[1];
    const float* node_W     = (const float*)d_in[2];
    const float* node_b     = (const float*)d_in[3];
    const int*   path_nodes = (const int*)d_in[4];
    const int*   path_bits  = (const int*)d_in[5];
    const void*  path_mask  = (const void*)d_in[6];
    float* out = (float*)d_out;
    float* partial = (float*)d_ws;

    const int T   = in_sizes[0] / HID;        // B*S = 2048 (in_sizes are elem counts)
    const int Vm1 = in_sizes[3] / 2;          // V-1
    const int V   = Vm1 + 1;
    const int D   = in_sizes[4] / V;          // padded path depth (~20)

    const int nslot = T * WPB;                // 8192, multiple of 4

    huffman_token_kernel<<<dim3(T), dim3(NTHREADS), 0, stream>>>(
        hidden, target, node_W, node_b, path_nodes, path_bits, path_mask,
        partial, D);

    huffman_reduce_kernel<<<dim3(1), dim3(RTHREADS), 0, stream>>>(
        partial, out, nslot / 4);
}